// Round 1
// baseline (171.654 us; speedup 1.0000x reference)
//
#include <hip/hip_runtime.h>
#include <math.h>

// out[n] = sum_k amp_k * exp(-0.5 * (x_n^T A_k x_n - 2 x_n . b_k + c_k))
//        = sum_k exp2( g_k . p_n )
// g_k = -0.5*log2(e) * (A00,A11,A22, 2A01,2A02,2A12, -2b0,-2b1,-2b2, c) + (0,...,0, log2(amp_k))
// p_n = (x0^2, x1^2, x2^2, x0x1, x0x2, x1x2, x0, x1, x2, 1)

__device__ __forceinline__ float fast_exp2(float t) {
#if __has_builtin(__builtin_amdgcn_exp2f)
    return __builtin_amdgcn_exp2f(t);
#else
    return exp2f(t);
#endif
}

__global__ __launch_bounds__(256) void gmf_precompute(
        const float* __restrict__ means,
        const float* __restrict__ log_scales,
        const float* __restrict__ quats,
        const float* __restrict__ log_amps,
        float* __restrict__ gp, int K) {
    int k = blockIdx.x * blockDim.x + threadIdx.x;
    if (k >= K) return;

    float qw = quats[4*k+0], qx = quats[4*k+1], qy = quats[4*k+2], qz = quats[4*k+3];
    float qn = rsqrtf(qw*qw + qx*qx + qy*qy + qz*qz);
    qw *= qn; qx *= qn; qy *= qn; qz *= qn;

    float r00 = 1.f - 2.f*(qy*qy + qz*qz);
    float r01 = 2.f*(qx*qy - qw*qz);
    float r02 = 2.f*(qx*qz + qw*qy);
    float r10 = 2.f*(qx*qy + qw*qz);
    float r11 = 1.f - 2.f*(qx*qx + qz*qz);
    float r12 = 2.f*(qy*qz - qw*qx);
    float r20 = 2.f*(qx*qz - qw*qy);
    float r21 = 2.f*(qy*qz + qw*qx);
    float r22 = 1.f - 2.f*(qx*qx + qy*qy);

    float s0 = fminf(fmaxf(expf(log_scales[3*k+0]), 1e-5f), 100.f);
    float s1 = fminf(fmaxf(expf(log_scales[3*k+1]), 1e-5f), 100.f);
    float s2 = fminf(fmaxf(expf(log_scales[3*k+2]), 1e-5f), 100.f);
    float v0 = s0*s0, v1 = s1*s1, v2 = s2*s2;

    // Sigma = R diag(v) R^T + 1e-5 I  (symmetric)
    float S00 = r00*r00*v0 + r01*r01*v1 + r02*r02*v2 + 1e-5f;
    float S11 = r10*r10*v0 + r11*r11*v1 + r12*r12*v2 + 1e-5f;
    float S22 = r20*r20*v0 + r21*r21*v1 + r22*r22*v2 + 1e-5f;
    float S01 = r00*r10*v0 + r01*r11*v1 + r02*r12*v2;
    float S02 = r00*r20*v0 + r01*r21*v1 + r02*r22*v2;
    float S12 = r10*r20*v0 + r11*r21*v1 + r12*r22*v2;

    // A = inv(Sigma) via adjugate (symmetric)
    float c00 = S11*S22 - S12*S12;
    float c01 = S02*S12 - S01*S22;
    float c02 = S01*S12 - S02*S11;
    float det = S00*c00 + S01*c01 + S02*c02;
    float id  = 1.f/det;
    float A00 = c00*id, A01 = c01*id, A02 = c02*id;
    float A11 = (S00*S22 - S02*S02)*id;
    float A12 = (S01*S02 - S00*S12)*id;
    float A22 = (S00*S11 - S01*S01)*id;

    float m0 = means[3*k+0], m1 = means[3*k+1], m2 = means[3*k+2];
    float b0 = A00*m0 + A01*m1 + A02*m2;
    float b1 = A01*m0 + A11*m1 + A12*m2;
    float b2 = A02*m0 + A12*m1 + A22*m2;
    float cc = b0*m0 + b1*m1 + b2*m2;

    float la = fminf(fmaxf(log_amps[k], -10.f), 6.f);
    const float L2E = 1.4426950408889634f;
    const float h = -0.5f * L2E;

    gp[10*k+0] = h*A00;
    gp[10*k+1] = h*A11;
    gp[10*k+2] = h*A22;
    gp[10*k+3] = 2.f*h*A01;
    gp[10*k+4] = 2.f*h*A02;
    gp[10*k+5] = 2.f*h*A12;
    gp[10*k+6] = L2E*b0;   // -0.5*(-2 b0) = +b0, scaled by log2(e)
    gp[10*k+7] = L2E*b1;
    gp[10*k+8] = L2E*b2;
    gp[10*k+9] = h*cc + L2E*la;
}

__global__ __launch_bounds__(256) void gmf_main(
        const float* __restrict__ x,
        const float* __restrict__ gp,
        float* __restrict__ out, int N, int K) {
    int n = blockIdx.x * blockDim.x + threadIdx.x;
    if (n >= N) return;

    float x0 = x[3*n+0], x1 = x[3*n+1], x2 = x[3*n+2];
    float p00 = x0*x0, p11 = x1*x1, p22 = x2*x2;
    float p01 = x0*x1, p02 = x0*x2, p12 = x1*x2;

    float acc0 = 0.f, acc1 = 0.f, acc2 = 0.f, acc3 = 0.f;

#define GMF_TERM(KK, ACC) { const float* g = gp + 10*(KK);                         \
    float t = g[9];                                                                \
    t = fmaf(g[0], p00, t); t = fmaf(g[1], p11, t); t = fmaf(g[2], p22, t);        \
    t = fmaf(g[3], p01, t); t = fmaf(g[4], p02, t); t = fmaf(g[5], p12, t);        \
    t = fmaf(g[6], x0, t);  t = fmaf(g[7], x1, t);  t = fmaf(g[8], x2, t);         \
    ACC += fast_exp2(t); }

    int k = 0;
    for (; k + 3 < K; k += 4) {
        GMF_TERM(k + 0, acc0)
        GMF_TERM(k + 1, acc1)
        GMF_TERM(k + 2, acc2)
        GMF_TERM(k + 3, acc3)
    }
    for (; k < K; ++k) {
        GMF_TERM(k, acc0)
    }
#undef GMF_TERM

    out[n] = (acc0 + acc1) + (acc2 + acc3);
}

extern "C" void kernel_launch(void* const* d_in, const int* in_sizes, int n_in,
                              void* d_out, int out_size, void* d_ws, size_t ws_size,
                              hipStream_t stream) {
    const float* x          = (const float*)d_in[0];
    const float* means      = (const float*)d_in[1];
    const float* log_scales = (const float*)d_in[2];
    const float* quats      = (const float*)d_in[3];
    const float* log_amps   = (const float*)d_in[4];
    float* out = (float*)d_out;
    float* gp  = (float*)d_ws;   // 10 floats per Gaussian

    int K = in_sizes[4];   // log_amplitudes element count == K_GAUSS
    int N = out_size;      // one output per point

    gmf_precompute<<<(K + 255) / 256, 256, 0, stream>>>(means, log_scales, quats, log_amps, gp, K);
    gmf_main<<<(N + 255) / 256, 256, 0, stream>>>(x, gp, out, N, K);
}

// Round 2
// 91.294 us; speedup vs baseline: 1.8802x; 1.8802x over previous
//
#include <hip/hip_runtime.h>
#include <math.h>

// out[n] = sum_k amp_k * exp(-0.5 * (x_n^T A_k x_n - 2 x_n . b_k + c_k))
//        = sum_k exp2( g_k . p_n )
// g_k (padded to 16 floats for aligned s_load_dwordx8+x2):
//   h*(A00,A11,A22), 2h*(A01,A02,A12), L2E*(b0,b1,b2), h*c + log2(amp)
// p_n = (x0^2, x1^2, x2^2, x0x1, x0x2, x1x2, x0, x1, x2, 1)

typedef float v2f __attribute__((ext_vector_type(2)));

__device__ __forceinline__ float fast_exp2(float t) {
#if __has_builtin(__builtin_amdgcn_exp2f)
    return __builtin_amdgcn_exp2f(t);
#else
    return exp2f(t);
#endif
}

__device__ __forceinline__ v2f pkfma(float a, v2f b, v2f c) {
    v2f av = {a, a};
    return __builtin_elementwise_fma(av, b, c);
}

#define GP_STRIDE 16

__global__ __launch_bounds__(256) void gmf_precompute(
        const float* __restrict__ means,
        const float* __restrict__ log_scales,
        const float* __restrict__ quats,
        const float* __restrict__ log_amps,
        float* __restrict__ gp, int K) {
    int k = blockIdx.x * blockDim.x + threadIdx.x;
    if (k >= K) return;

    float qw = quats[4*k+0], qx = quats[4*k+1], qy = quats[4*k+2], qz = quats[4*k+3];
    float qn = rsqrtf(qw*qw + qx*qx + qy*qy + qz*qz);
    qw *= qn; qx *= qn; qy *= qn; qz *= qn;

    float r00 = 1.f - 2.f*(qy*qy + qz*qz);
    float r01 = 2.f*(qx*qy - qw*qz);
    float r02 = 2.f*(qx*qz + qw*qy);
    float r10 = 2.f*(qx*qy + qw*qz);
    float r11 = 1.f - 2.f*(qx*qx + qz*qz);
    float r12 = 2.f*(qy*qz - qw*qx);
    float r20 = 2.f*(qx*qz - qw*qy);
    float r21 = 2.f*(qy*qz + qw*qx);
    float r22 = 1.f - 2.f*(qx*qx + qy*qy);

    float s0 = fminf(fmaxf(expf(log_scales[3*k+0]), 1e-5f), 100.f);
    float s1 = fminf(fmaxf(expf(log_scales[3*k+1]), 1e-5f), 100.f);
    float s2 = fminf(fmaxf(expf(log_scales[3*k+2]), 1e-5f), 100.f);
    float v0 = s0*s0, v1 = s1*s1, v2 = s2*s2;

    float S00 = r00*r00*v0 + r01*r01*v1 + r02*r02*v2 + 1e-5f;
    float S11 = r10*r10*v0 + r11*r11*v1 + r12*r12*v2 + 1e-5f;
    float S22 = r20*r20*v0 + r21*r21*v1 + r22*r22*v2 + 1e-5f;
    float S01 = r00*r10*v0 + r01*r11*v1 + r02*r12*v2;
    float S02 = r00*r20*v0 + r01*r21*v1 + r02*r22*v2;
    float S12 = r10*r20*v0 + r11*r21*v1 + r12*r22*v2;

    float c00 = S11*S22 - S12*S12;
    float c01 = S02*S12 - S01*S22;
    float c02 = S01*S12 - S02*S11;
    float det = S00*c00 + S01*c01 + S02*c02;
    float id  = 1.f/det;
    float A00 = c00*id, A01 = c01*id, A02 = c02*id;
    float A11 = (S00*S22 - S02*S02)*id;
    float A12 = (S01*S02 - S00*S12)*id;
    float A22 = (S00*S11 - S01*S01)*id;

    float m0 = means[3*k+0], m1 = means[3*k+1], m2 = means[3*k+2];
    float b0 = A00*m0 + A01*m1 + A02*m2;
    float b1 = A01*m0 + A11*m1 + A12*m2;
    float b2 = A02*m0 + A12*m1 + A22*m2;
    float cc = b0*m0 + b1*m1 + b2*m2;

    float la = fminf(fmaxf(log_amps[k], -10.f), 6.f);
    const float L2E = 1.4426950408889634f;
    const float h = -0.5f * L2E;

    float* g = gp + GP_STRIDE * k;
    g[0] = h*A00;
    g[1] = h*A11;
    g[2] = h*A22;
    g[3] = 2.f*h*A01;
    g[4] = 2.f*h*A02;
    g[5] = 2.f*h*A12;
    g[6] = L2E*b0;
    g[7] = L2E*b1;
    g[8] = L2E*b2;
    g[9] = h*cc + L2E*la;
    g[10] = 0.f; g[11] = 0.f; g[12] = 0.f; g[13] = 0.f; g[14] = 0.f; g[15] = 0.f;
}

// Each thread: 2 points (packed f32), one K-chunk (blockIdx.y). Partials to ws.
__global__ __launch_bounds__(256) void gmf_main(
        const float* __restrict__ x,
        const float* __restrict__ gp,
        float* __restrict__ partial,   // [KS][N]; if KS==1 this is `out`
        int N, int K, int ksplit) {
    int i = blockIdx.x * blockDim.x + threadIdx.x;   // pair index
    int n0 = 2 * i;
    if (n0 >= N) return;
    int split = blockIdx.y;

    int chunk = (K + ksplit - 1) / ksplit;
    int kbeg = split * chunk;
    int kend = min(K, kbeg + chunk);

    bool full = (n0 + 1 < N);
    float ax0 = x[3*n0+0], ax1 = x[3*n0+1], ax2 = x[3*n0+2];
    float bx0 = ax0, bx1 = ax1, bx2 = ax2;
    if (full) { bx0 = x[3*n0+3]; bx1 = x[3*n0+4]; bx2 = x[3*n0+5]; }

    v2f X0 = {ax0, bx0}, X1 = {ax1, bx1}, X2 = {ax2, bx2};
    v2f P00 = X0*X0, P11 = X1*X1, P22 = X2*X2;
    v2f P01 = X0*X1, P02 = X0*X2, P12 = X1*X2;

    v2f acc0 = {0.f, 0.f};
    v2f acc1 = {0.f, 0.f};

#define GMF_TERM(KK, ACC) { const float* g = gp + GP_STRIDE*(KK);                  \
    v2f t = {g[9], g[9]};                                                          \
    t = pkfma(g[0], P00, t); t = pkfma(g[1], P11, t); t = pkfma(g[2], P22, t);     \
    t = pkfma(g[3], P01, t); t = pkfma(g[4], P02, t); t = pkfma(g[5], P12, t);     \
    t = pkfma(g[6], X0, t);  t = pkfma(g[7], X1, t);  t = pkfma(g[8], X2, t);      \
    v2f e = {fast_exp2(t.x), fast_exp2(t.y)};                                      \
    ACC += e; }

    int k = kbeg;
    for (; k + 1 < kend; k += 2) {
        GMF_TERM(k + 0, acc0)
        GMF_TERM(k + 1, acc1)
    }
    for (; k < kend; ++k) {
        GMF_TERM(k, acc0)
    }
#undef GMF_TERM

    v2f r = acc0 + acc1;
    float* dst = partial + (size_t)split * N + n0;
    if (full) {
        *(v2f*)dst = r;
    } else {
        dst[0] = r.x;
    }
}

__global__ __launch_bounds__(256) void gmf_reduce(
        const float* __restrict__ partial,
        float* __restrict__ out, int N, int ksplit) {
    int j = blockIdx.x * blockDim.x + threadIdx.x;   // quad index
    int n0 = 4 * j;
    if (n0 >= N) return;
    if (n0 + 3 < N) {
        float4 s = {0.f, 0.f, 0.f, 0.f};
        for (int sp = 0; sp < ksplit; ++sp) {
            float4 v = *(const float4*)(partial + (size_t)sp * N + n0);
            s.x += v.x; s.y += v.y; s.z += v.z; s.w += v.w;
        }
        *(float4*)(out + n0) = s;
    } else {
        for (int n = n0; n < N; ++n) {
            float s = 0.f;
            for (int sp = 0; sp < ksplit; ++sp) s += partial[(size_t)sp * N + n];
            out[n] = s;
        }
    }
}

extern "C" void kernel_launch(void* const* d_in, const int* in_sizes, int n_in,
                              void* d_out, int out_size, void* d_ws, size_t ws_size,
                              hipStream_t stream) {
    const float* x          = (const float*)d_in[0];
    const float* means      = (const float*)d_in[1];
    const float* log_scales = (const float*)d_in[2];
    const float* quats      = (const float*)d_in[3];
    const float* log_amps   = (const float*)d_in[4];
    float* out = (float*)d_out;

    int K = in_sizes[4];
    int N = out_size;

    size_t gp_bytes = (size_t)K * GP_STRIDE * sizeof(float);
    float* gp = (float*)d_ws;

    // Pick largest ksplit whose partial buffer fits in the remaining workspace.
    int ksplit = 1;
    for (int ks = 8; ks >= 2; ks >>= 1) {
        if (gp_bytes + (size_t)ks * N * sizeof(float) <= ws_size) { ksplit = ks; break; }
    }
    bool use_partial = (ksplit > 1) &&
                       (gp_bytes + (size_t)ksplit * N * sizeof(float) <= ws_size);

    gmf_precompute<<<(K + 255) / 256, 256, 0, stream>>>(means, log_scales, quats, log_amps, gp, K);

    int npairs = (N + 1) / 2;
    dim3 grid((npairs + 255) / 256, use_partial ? ksplit : 1);

    if (use_partial) {
        float* partial = (float*)((char*)d_ws + gp_bytes);
        gmf_main<<<grid, 256, 0, stream>>>(x, gp, partial, N, K, ksplit);
        int nquads = (N + 3) / 4;
        gmf_reduce<<<(nquads + 255) / 256, 256, 0, stream>>>(partial, out, N, ksplit);
    } else {
        gmf_main<<<grid, 256, 0, stream>>>(x, gp, out, N, K, 1);
    }
}

// Round 3
// 62.541 us; speedup vs baseline: 2.7447x; 1.4598x over previous
//
#include <hip/hip_runtime.h>
#include <math.h>

// t[n,k] = sum_{j<10} P[n,j] * G[k,j];  out[n] = sum_k exp2(t[n,k])
// P = (x0^2,x1^2,x2^2, x0x1,x0x2,x1x2, x0,x1,x2, 1)
// G = h*(A00,A11,A22), 2h*(A01,A02,A12), L2E*(b0,b1,b2), h*c + log2(amp),  h = -0.5*log2(e)
//
// MFMA f16 split-2 trick (one mfma_f32_16x16x32_f16 per 16x16 tile):
//   A cols [0..31] = [Phi(10) | Phi(10) | Plo(10) | 0 0]
//   B rows [0..31] = [Ghi(10) | Glo(10) | Ghi(10) | 0 0]
//   => t = Phi.Ghi + Phi.Glo + Plo.Ghi  (~22-bit precise product)
//
// Fragment layout (gfx950 16x16x32): A: lane l -> row l&15, k = (l>>4)*8 + j
//                                    B: lane l -> col l&15, k = (l>>4)*8 + j
//                                    C: lane l -> col l&15, row = (l>>4)*4 + reg

typedef _Float16 half8 __attribute__((ext_vector_type(8)));
typedef float    f32x4 __attribute__((ext_vector_type(4)));

#define PT  4   // point-tiles (16 points each) per wave
#define WPB 4   // waves per block (256 threads)

__device__ __forceinline__ float fast_exp2(float t) {
#if __has_builtin(__builtin_amdgcn_exp2f)
    return __builtin_amdgcn_exp2f(t);
#else
    return exp2f(t);
#endif
}

__global__ __launch_bounds__(256) void gmf_precompute(
        const float* __restrict__ means,
        const float* __restrict__ log_scales,
        const float* __restrict__ quats,
        const float* __restrict__ log_amps,
        _Float16* __restrict__ Bf, int K, int KT) {
    int k = blockIdx.x * blockDim.x + threadIdx.x;
    if (k >= KT * 16) return;

    float gc[10];
    if (k < K) {
        float qw = quats[4*k+0], qx = quats[4*k+1], qy = quats[4*k+2], qz = quats[4*k+3];
        float qn = rsqrtf(qw*qw + qx*qx + qy*qy + qz*qz);
        qw *= qn; qx *= qn; qy *= qn; qz *= qn;

        float r00 = 1.f - 2.f*(qy*qy + qz*qz);
        float r01 = 2.f*(qx*qy - qw*qz);
        float r02 = 2.f*(qx*qz + qw*qy);
        float r10 = 2.f*(qx*qy + qw*qz);
        float r11 = 1.f - 2.f*(qx*qx + qz*qz);
        float r12 = 2.f*(qy*qz - qw*qx);
        float r20 = 2.f*(qx*qz - qw*qy);
        float r21 = 2.f*(qy*qz + qw*qx);
        float r22 = 1.f - 2.f*(qx*qx + qy*qy);

        float s0 = fminf(fmaxf(expf(log_scales[3*k+0]), 1e-5f), 100.f);
        float s1 = fminf(fmaxf(expf(log_scales[3*k+1]), 1e-5f), 100.f);
        float s2 = fminf(fmaxf(expf(log_scales[3*k+2]), 1e-5f), 100.f);
        float v0 = s0*s0, v1 = s1*s1, v2 = s2*s2;

        float S00 = r00*r00*v0 + r01*r01*v1 + r02*r02*v2 + 1e-5f;
        float S11 = r10*r10*v0 + r11*r11*v1 + r12*r12*v2 + 1e-5f;
        float S22 = r20*r20*v0 + r21*r21*v1 + r22*r22*v2 + 1e-5f;
        float S01 = r00*r10*v0 + r01*r11*v1 + r02*r12*v2;
        float S02 = r00*r20*v0 + r01*r21*v1 + r02*r22*v2;
        float S12 = r10*r20*v0 + r11*r21*v1 + r12*r22*v2;

        float c00 = S11*S22 - S12*S12;
        float c01 = S02*S12 - S01*S22;
        float c02 = S01*S12 - S02*S11;
        float det = S00*c00 + S01*c01 + S02*c02;
        float id  = 1.f/det;
        float A00 = c00*id, A01 = c01*id, A02 = c02*id;
        float A11 = (S00*S22 - S02*S02)*id;
        float A12 = (S01*S02 - S00*S12)*id;
        float A22 = (S00*S11 - S01*S01)*id;

        float m0 = means[3*k+0], m1 = means[3*k+1], m2 = means[3*k+2];
        float b0 = A00*m0 + A01*m1 + A02*m2;
        float b1 = A01*m0 + A11*m1 + A12*m2;
        float b2 = A02*m0 + A12*m1 + A22*m2;
        float cc = b0*m0 + b1*m1 + b2*m2;

        float la = fminf(fmaxf(log_amps[k], -10.f), 6.f);
        const float L2E = 1.4426950408889634f;
        const float h = -0.5f * L2E;

        gc[0] = h*A00; gc[1] = h*A11; gc[2] = h*A22;
        gc[3] = 2.f*h*A01; gc[4] = 2.f*h*A02; gc[5] = 2.f*h*A12;
        gc[6] = L2E*b0; gc[7] = L2E*b1; gc[8] = L2E*b2;
        gc[9] = h*cc + L2E*la;
    } else {
        #pragma unroll
        for (int j = 0; j < 10; ++j) gc[j] = 0.f;
        gc[9] = -60000.f;   // pad gaussian contributes exp2(-big) = 0
    }

    _Float16 gh[10], gl[10];
    #pragma unroll
    for (int j = 0; j < 10; ++j) {
        gh[j] = (_Float16)gc[j];
        gl[j] = (_Float16)(gc[j] - (float)gh[j]);
    }

    int kt = k >> 4, c = k & 15;
    _Float16* dst = Bf + (size_t)kt * 64 * 8;   // tile base: 64 lanes x 8 halves
    #pragma unroll 32
    for (int r = 0; r < 32; ++r) {
        int lg = r >> 3, j = r & 7;
        _Float16 v = (r < 10) ? gh[r]
                   : (r < 20) ? gl[r-10]
                   : (r < 30) ? gh[r-20]
                   : (_Float16)0.f;
        dst[((size_t)lg*16 + c)*8 + j] = v;
    }
}

__global__ __launch_bounds__(256) void gmf_main(
        const float* __restrict__ x,
        const half8* __restrict__ Bf,
        float* __restrict__ out, int N, int KT, int PTtot) {
    int tid  = threadIdx.x;
    int lane = tid & 63;
    int wid  = tid >> 6;
    int gwid = blockIdx.x * WPB + wid;
    int lg = lane >> 4;    // lane group: A k-block / C row-block
    int lr = lane & 15;    // A row / C col

    half8 afr[PT];
    f32x4 acc[PT];
    int   pts[PT];
    bool any_valid = false;

    #pragma unroll
    for (int t = 0; t < PT; ++t) {
        int pt = gwid * PT + t;
        pts[t] = pt;
        acc[t] = (f32x4){0.f, 0.f, 0.f, 0.f};
        if (pt < PTtot) any_valid = true;

        int n = pt * 16 + lr;
        float x0 = 0.f, x1 = 0.f, x2 = 0.f;
        if (pt < PTtot && n < N) { x0 = x[3*n]; x1 = x[3*n+1]; x2 = x[3*n+2]; }

        float P0 = x0*x0, P1 = x1*x1, P2 = x2*x2;
        float P3 = x0*x1, P4 = x0*x2, P5 = x1*x2;

        _Float16 h0 = (_Float16)P0, h1 = (_Float16)P1, h2 = (_Float16)P2;
        _Float16 h3 = (_Float16)P3, h4 = (_Float16)P4, h5 = (_Float16)P5;
        _Float16 h6 = (_Float16)x0, h7 = (_Float16)x1, h8 = (_Float16)x2;
        _Float16 h9 = (_Float16)1.f;
        _Float16 l0 = (_Float16)(P0 - (float)h0), l1 = (_Float16)(P1 - (float)h1);
        _Float16 l2 = (_Float16)(P2 - (float)h2), l3 = (_Float16)(P3 - (float)h3);
        _Float16 l4 = (_Float16)(P4 - (float)h4), l5 = (_Float16)(P5 - (float)h5);
        _Float16 l6 = (_Float16)(x0 - (float)h6), l7 = (_Float16)(x1 - (float)h7);
        _Float16 l8 = (_Float16)(x2 - (float)h8), l9 = (_Float16)0.f;
        _Float16 z  = (_Float16)0.f;

        half8 a;
        if      (lg == 0) a = (half8){h0,h1,h2,h3,h4,h5,h6,h7};   // cols 0-7:   Phi[0..7]
        else if (lg == 1) a = (half8){h8,h9,h0,h1,h2,h3,h4,h5};   // cols 8-15:  Phi[8],Phi[9],Phi[0..5]
        else if (lg == 2) a = (half8){h6,h7,h8,h9,l0,l1,l2,l3};   // cols 16-23: Phi[6..9],Plo[0..3]
        else              a = (half8){l4,l5,l6,l7,l8,l9,z,z};     // cols 24-31: Plo[4..9],0,0
        afr[t] = a;
    }

    if (!any_valid) return;

    const half8* bp = Bf + lane;
    #pragma unroll 2
    for (int kt = 0; kt < KT; ++kt) {
        half8 b = bp[(size_t)kt * 64];
        #pragma unroll
        for (int t = 0; t < PT; ++t) {
            f32x4 c = __builtin_amdgcn_mfma_f32_16x16x32_f16(
                afr[t], b, (f32x4){0.f, 0.f, 0.f, 0.f}, 0, 0, 0);
            acc[t].x += fast_exp2(c.x);
            acc[t].y += fast_exp2(c.y);
            acc[t].z += fast_exp2(c.z);
            acc[t].w += fast_exp2(c.w);
        }
    }

    #pragma unroll
    for (int t = 0; t < PT; ++t) {
        f32x4 a = acc[t];
        #pragma unroll
        for (int m = 1; m <= 8; m <<= 1) {   // reduce over 16 cols (lanes sharing lg)
            a.x += __shfl_xor(a.x, m);
            a.y += __shfl_xor(a.y, m);
            a.z += __shfl_xor(a.z, m);
            a.w += __shfl_xor(a.w, m);
        }
        if (lr == 0 && pts[t] < PTtot) {
            int n0 = pts[t] * 16 + lg * 4;   // rows lg*4 .. lg*4+3
            if (n0     < N) out[n0]     = a.x;
            if (n0 + 1 < N) out[n0 + 1] = a.y;
            if (n0 + 2 < N) out[n0 + 2] = a.z;
            if (n0 + 3 < N) out[n0 + 3] = a.w;
        }
    }
}

extern "C" void kernel_launch(void* const* d_in, const int* in_sizes, int n_in,
                              void* d_out, int out_size, void* d_ws, size_t ws_size,
                              hipStream_t stream) {
    const float* x          = (const float*)d_in[0];
    const float* means      = (const float*)d_in[1];
    const float* log_scales = (const float*)d_in[2];
    const float* quats      = (const float*)d_in[3];
    const float* log_amps   = (const float*)d_in[4];
    float* out = (float*)d_out;

    int K = in_sizes[4];
    int N = out_size;
    int KT = (K + 15) / 16;
    int PTtot = (N + 15) / 16;

    _Float16* Bf = (_Float16*)d_ws;   // KT * 64 lanes * 8 halves = KT KiB

    gmf_precompute<<<(KT*16 + 255) / 256, 256, 0, stream>>>(
        means, log_scales, quats, log_amps, Bf, K, KT);

    int waves  = (PTtot + PT - 1) / PT;
    int blocks = (waves + WPB - 1) / WPB;
    gmf_main<<<blocks, 256, 0, stream>>>(x, (const half8*)d_ws, out, N, KT, PTtot);
}

// Round 4
// 50.380 us; speedup vs baseline: 3.4072x; 1.2414x over previous
//
#include <hip/hip_runtime.h>
#include <math.h>

// t[n,k] = sum_{j<10} P[n,j] * G[k,j];  out[n] = sum_k exp2(t[n,k])
// P = (x0^2,x1^2,x2^2, x0x1,x0x2,x1x2, x0,x1,x2, 1)
// G = h*(A00,A11,A22), 2h*(A01,A02,A12), L2E*(b0,b1,b2), h*c + log2(amp),  h = -0.5*log2(e)
//
// MFMA f16 split-2 trick (one mfma_f32_16x16x32_f16 per 16x16 tile):
//   A cols [0..31] = [Phi(10) | Phi(10) | Plo(10) | 0 0]
//   B rows [0..31] = [Ghi(10) | Glo(10) | Ghi(10) | 0 0]
//   => t = Phi.Ghi + Phi.Glo + Plo.Ghi  (~22-bit precise product)
//
// Fragment layout (gfx950 16x16x32): A: lane l -> row l&15, k = (l>>4)*8 + j
//                                    B: lane l -> col l&15, k = (l>>4)*8 + j
//                                    C: lane l -> col l&15, row = (l>>4)*4 + reg

typedef _Float16 half8 __attribute__((ext_vector_type(8)));
typedef float    f32x4 __attribute__((ext_vector_type(4)));

#define PT     4   // point-tiles (16 points each) per wave
#define WPB    4   // waves per block (256 threads)
#define KSPLIT 4   // gaussian-tile splits (blockIdx.y)

__device__ __forceinline__ float fast_exp2(float t) {
#if __has_builtin(__builtin_amdgcn_exp2f)
    return __builtin_amdgcn_exp2f(t);
#else
    return exp2f(t);
#endif
}

__global__ __launch_bounds__(256) void gmf_precompute(
        const float* __restrict__ means,
        const float* __restrict__ log_scales,
        const float* __restrict__ quats,
        const float* __restrict__ log_amps,
        _Float16* __restrict__ Bf, int K, int KT) {
    int k = blockIdx.x * blockDim.x + threadIdx.x;
    if (k >= KT * 16) return;

    float gc[10];
    if (k < K) {
        float qw = quats[4*k+0], qx = quats[4*k+1], qy = quats[4*k+2], qz = quats[4*k+3];
        float qn = rsqrtf(qw*qw + qx*qx + qy*qy + qz*qz);
        qw *= qn; qx *= qn; qy *= qn; qz *= qn;

        float r00 = 1.f - 2.f*(qy*qy + qz*qz);
        float r01 = 2.f*(qx*qy - qw*qz);
        float r02 = 2.f*(qx*qz + qw*qy);
        float r10 = 2.f*(qx*qy + qw*qz);
        float r11 = 1.f - 2.f*(qx*qx + qz*qz);
        float r12 = 2.f*(qy*qz - qw*qx);
        float r20 = 2.f*(qx*qz - qw*qy);
        float r21 = 2.f*(qy*qz + qw*qx);
        float r22 = 1.f - 2.f*(qx*qx + qy*qy);

        float s0 = fminf(fmaxf(expf(log_scales[3*k+0]), 1e-5f), 100.f);
        float s1 = fminf(fmaxf(expf(log_scales[3*k+1]), 1e-5f), 100.f);
        float s2 = fminf(fmaxf(expf(log_scales[3*k+2]), 1e-5f), 100.f);
        float v0 = s0*s0, v1 = s1*s1, v2 = s2*s2;

        float S00 = r00*r00*v0 + r01*r01*v1 + r02*r02*v2 + 1e-5f;
        float S11 = r10*r10*v0 + r11*r11*v1 + r12*r12*v2 + 1e-5f;
        float S22 = r20*r20*v0 + r21*r21*v1 + r22*r22*v2 + 1e-5f;
        float S01 = r00*r10*v0 + r01*r11*v1 + r02*r12*v2;
        float S02 = r00*r20*v0 + r01*r21*v1 + r02*r22*v2;
        float S12 = r10*r20*v0 + r11*r21*v1 + r12*r22*v2;

        float c00 = S11*S22 - S12*S12;
        float c01 = S02*S12 - S01*S22;
        float c02 = S01*S12 - S02*S11;
        float det = S00*c00 + S01*c01 + S02*c02;
        float id  = 1.f/det;
        float A00 = c00*id, A01 = c01*id, A02 = c02*id;
        float A11 = (S00*S22 - S02*S02)*id;
        float A12 = (S01*S02 - S00*S12)*id;
        float A22 = (S00*S11 - S01*S01)*id;

        float m0 = means[3*k+0], m1 = means[3*k+1], m2 = means[3*k+2];
        float b0 = A00*m0 + A01*m1 + A02*m2;
        float b1 = A01*m0 + A11*m1 + A12*m2;
        float b2 = A02*m0 + A12*m1 + A22*m2;
        float cc = b0*m0 + b1*m1 + b2*m2;

        float la = fminf(fmaxf(log_amps[k], -10.f), 6.f);
        const float L2E = 1.4426950408889634f;
        const float h = -0.5f * L2E;

        gc[0] = h*A00; gc[1] = h*A11; gc[2] = h*A22;
        gc[3] = 2.f*h*A01; gc[4] = 2.f*h*A02; gc[5] = 2.f*h*A12;
        gc[6] = L2E*b0; gc[7] = L2E*b1; gc[8] = L2E*b2;
        gc[9] = h*cc + L2E*la;
    } else {
        #pragma unroll
        for (int j = 0; j < 10; ++j) gc[j] = 0.f;
        gc[9] = -60000.f;   // pad gaussian contributes exp2(-big) = 0
    }

    _Float16 gh[10], gl[10];
    #pragma unroll
    for (int j = 0; j < 10; ++j) {
        gh[j] = (_Float16)gc[j];
        gl[j] = (_Float16)(gc[j] - (float)gh[j]);
    }

    int kt = k >> 4, c = k & 15;
    _Float16* dst = Bf + (size_t)kt * 64 * 8;   // tile base: 64 lanes x 8 halves
    #pragma unroll 32
    for (int r = 0; r < 32; ++r) {
        int lg = r >> 3, j = r & 7;
        _Float16 v = (r < 10) ? gh[r]
                   : (r < 20) ? gl[r-10]
                   : (r < 30) ? gh[r-20]
                   : (_Float16)0.f;
        dst[((size_t)lg*16 + c)*8 + j] = v;
    }
}

__global__ __launch_bounds__(256) void gmf_main(
        const float* __restrict__ x,
        const half8* __restrict__ Bf,
        float* __restrict__ partial,   // [ksplit][N] (or out directly if ksplit==1)
        int N, int KT, int PTtot, int ksplit) {
    int tid  = threadIdx.x;
    int lane = tid & 63;
    int wid  = tid >> 6;
    int gwid = blockIdx.x * WPB + wid;
    int lg = lane >> 4;    // lane group: A k-block / C row-block
    int lr = lane & 15;    // A row / C col

    int split = blockIdx.y;
    int chunk = (KT + ksplit - 1) / ksplit;
    int kbeg = split * chunk;
    int kend = min(KT, kbeg + chunk);

    half8 afr[PT];
    f32x4 acc[PT];
    int   pts[PT];
    bool any_valid = false;

    #pragma unroll
    for (int t = 0; t < PT; ++t) {
        int pt = gwid * PT + t;
        pts[t] = pt;
        acc[t] = (f32x4){0.f, 0.f, 0.f, 0.f};
        if (pt < PTtot) any_valid = true;

        int n = pt * 16 + lr;
        float x0 = 0.f, x1 = 0.f, x2 = 0.f;
        if (pt < PTtot && n < N) { x0 = x[3*n]; x1 = x[3*n+1]; x2 = x[3*n+2]; }

        float P0 = x0*x0, P1 = x1*x1, P2 = x2*x2;
        float P3 = x0*x1, P4 = x0*x2, P5 = x1*x2;

        _Float16 h0 = (_Float16)P0, h1 = (_Float16)P1, h2 = (_Float16)P2;
        _Float16 h3 = (_Float16)P3, h4 = (_Float16)P4, h5 = (_Float16)P5;
        _Float16 h6 = (_Float16)x0, h7 = (_Float16)x1, h8 = (_Float16)x2;
        _Float16 h9 = (_Float16)1.f;
        _Float16 l0 = (_Float16)(P0 - (float)h0), l1 = (_Float16)(P1 - (float)h1);
        _Float16 l2 = (_Float16)(P2 - (float)h2), l3 = (_Float16)(P3 - (float)h3);
        _Float16 l4 = (_Float16)(P4 - (float)h4), l5 = (_Float16)(P5 - (float)h5);
        _Float16 l6 = (_Float16)(x0 - (float)h6), l7 = (_Float16)(x1 - (float)h7);
        _Float16 l8 = (_Float16)(x2 - (float)h8), l9 = (_Float16)0.f;
        _Float16 z  = (_Float16)0.f;

        half8 a;
        if      (lg == 0) a = (half8){h0,h1,h2,h3,h4,h5,h6,h7};   // cols 0-7:   Phi[0..7]
        else if (lg == 1) a = (half8){h8,h9,h0,h1,h2,h3,h4,h5};   // cols 8-15:  Phi[8],Phi[9],Phi[0..5]
        else if (lg == 2) a = (half8){h6,h7,h8,h9,l0,l1,l2,l3};   // cols 16-23: Phi[6..9],Plo[0..3]
        else              a = (half8){l4,l5,l6,l7,l8,l9,z,z};     // cols 24-31: Plo[4..9],0,0
        afr[t] = a;
    }

    if (!any_valid) return;

    const half8* bp = Bf + lane;
    #pragma unroll 4
    for (int kt = kbeg; kt < kend; ++kt) {
        half8 b = bp[(size_t)kt * 64];
        #pragma unroll
        for (int t = 0; t < PT; ++t) {
            f32x4 c = __builtin_amdgcn_mfma_f32_16x16x32_f16(
                afr[t], b, (f32x4){0.f, 0.f, 0.f, 0.f}, 0, 0, 0);
            acc[t].x += fast_exp2(c.x);
            acc[t].y += fast_exp2(c.y);
            acc[t].z += fast_exp2(c.z);
            acc[t].w += fast_exp2(c.w);
        }
    }

    float* dst_base = partial + (size_t)split * N;
    #pragma unroll
    for (int t = 0; t < PT; ++t) {
        f32x4 a = acc[t];
        #pragma unroll
        for (int m = 1; m <= 8; m <<= 1) {   // reduce over 16 cols (lanes sharing lg)
            a.x += __shfl_xor(a.x, m);
            a.y += __shfl_xor(a.y, m);
            a.z += __shfl_xor(a.z, m);
            a.w += __shfl_xor(a.w, m);
        }
        if (lr == 0 && pts[t] < PTtot) {
            int n0 = pts[t] * 16 + lg * 4;   // rows lg*4 .. lg*4+3
            if (n0     < N) dst_base[n0]     = a.x;
            if (n0 + 1 < N) dst_base[n0 + 1] = a.y;
            if (n0 + 2 < N) dst_base[n0 + 2] = a.z;
            if (n0 + 3 < N) dst_base[n0 + 3] = a.w;
        }
    }
}

__global__ __launch_bounds__(256) void gmf_reduce(
        const float* __restrict__ partial,
        float* __restrict__ out, int N, int ksplit) {
    int j = blockIdx.x * blockDim.x + threadIdx.x;   // quad index
    int n0 = 4 * j;
    if (n0 >= N) return;
    if (n0 + 3 < N) {
        float4 s = {0.f, 0.f, 0.f, 0.f};
        for (int sp = 0; sp < ksplit; ++sp) {
            float4 v = *(const float4*)(partial + (size_t)sp * N + n0);
            s.x += v.x; s.y += v.y; s.z += v.z; s.w += v.w;
        }
        *(float4*)(out + n0) = s;
    } else {
        for (int n = n0; n < N; ++n) {
            float s = 0.f;
            for (int sp = 0; sp < ksplit; ++sp) s += partial[(size_t)sp * N + n];
            out[n] = s;
        }
    }
}

extern "C" void kernel_launch(void* const* d_in, const int* in_sizes, int n_in,
                              void* d_out, int out_size, void* d_ws, size_t ws_size,
                              hipStream_t stream) {
    const float* x          = (const float*)d_in[0];
    const float* means      = (const float*)d_in[1];
    const float* log_scales = (const float*)d_in[2];
    const float* quats      = (const float*)d_in[3];
    const float* log_amps   = (const float*)d_in[4];
    float* out = (float*)d_out;

    int K = in_sizes[4];
    int N = out_size;
    int KT = (K + 15) / 16;
    int PTtot = (N + 15) / 16;

    size_t b_bytes = ((size_t)KT * 64 * 8 * sizeof(_Float16) + 255) & ~(size_t)255;
    _Float16* Bf = (_Float16*)d_ws;

    int ksplit = KSPLIT;
    size_t part_bytes = (size_t)ksplit * N * sizeof(float);
    bool use_partial = (b_bytes + part_bytes <= ws_size);
    if (!use_partial) ksplit = 1;

    gmf_precompute<<<(KT*16 + 255) / 256, 256, 0, stream>>>(
        means, log_scales, quats, log_amps, Bf, K, KT);

    int waves  = (PTtot + PT - 1) / PT;
    int blocks = (waves + WPB - 1) / WPB;
    dim3 grid(blocks, ksplit);

    if (use_partial) {
        float* partial = (float*)((char*)d_ws + b_bytes);
        gmf_main<<<grid, 256, 0, stream>>>((const float*)x, (const half8*)Bf, partial,
                                           N, KT, PTtot, ksplit);
        int nquads = (N + 3) / 4;
        gmf_reduce<<<(nquads + 255) / 256, 256, 0, stream>>>(partial, out, N, ksplit);
    } else {
        gmf_main<<<grid, 256, 0, stream>>>((const float*)x, (const half8*)Bf, out,
                                           N, KT, PTtot, 1);
    }
}